// Round 4
// baseline (683.776 us; speedup 1.0000x reference)
//
#include <hip/hip_runtime.h>

#define DIM 32
#define NB  6

typedef __attribute__((ext_vector_type(8)))  short short8;
typedef __attribute__((ext_vector_type(16))) float floatx16;

union S8I4 { short8 s; int i[4]; };

__device__ __forceinline__ unsigned short f2bf(float f) {
    unsigned u = __float_as_uint(f);
    return (unsigned short)((u + 0x7FFF + ((u >> 16) & 1)) >> 16);
}
__device__ __forceinline__ float bf2f(unsigned short b) {
    return __uint_as_float(((unsigned)b) << 16);
}
// B-frag slot (s,h,j) holds raw channel P; C/D reg (r,h) holds raw channel Q.
__device__ __forceinline__ int Pmap(int s, int h, int j) { return 16*s + 8*(j>>2) + 4*h + (j&3); }
__device__ __forceinline__ int Qmap(int p)               { int r = p & 15, h = p >> 4; return 8*(r>>2) + 4*h + (r&3); }

#define MFMA(a, b, c) __builtin_amdgcn_mfma_f32_32x32x16_bf16((a), (b), (c), 0, 0, 0)

// sin -> truncation hi/lo bf16 split, packed pairwise via v_perm_b32.
__device__ __forceinline__ void sinsplit(const floatx16& acc,
                                         short8& b1h, short8& b1l,
                                         short8& b2h, short8& b2l) {
    S8I4 nh1, nl1, nh2, nl2;
    #pragma unroll
    for (int q = 0; q < 4; ++q) {
        float s0 = __sinf(acc[2*q]), s1 = __sinf(acc[2*q+1]);
        unsigned a0 = __float_as_uint(s0), a1 = __float_as_uint(s1);
        nh1.i[q] = __builtin_amdgcn_perm(a1, a0, 0x07060302u);
        float l0 = s0 - __uint_as_float(a0 & 0xFFFF0000u);
        float l1 = s1 - __uint_as_float(a1 & 0xFFFF0000u);
        nl1.i[q] = __builtin_amdgcn_perm(__float_as_uint(l1), __float_as_uint(l0), 0x07060302u);
        float t0 = __sinf(acc[8+2*q]), t1 = __sinf(acc[8+2*q+1]);
        unsigned c0 = __float_as_uint(t0), c1 = __float_as_uint(t1);
        nh2.i[q] = __builtin_amdgcn_perm(c1, c0, 0x07060302u);
        float m0 = t0 - __uint_as_float(c0 & 0xFFFF0000u);
        float m1 = t1 - __uint_as_float(c1 & 0xFFFF0000u);
        nl2.i[q] = __builtin_amdgcn_perm(__float_as_uint(m1), __float_as_uint(m0), 0x07060302u);
    }
    b1h = nh1.s; b1l = nl1.s; b2h = nh2.s; b2l = nl2.s;
}

// LDS: 928 floats (3712 B) + 36992 shorts (73984 B) = 77696 B -> 2 blocks/CU.
#define LDS_BYTES 77696

__global__ __launch_bounds__(512, 4) void sep_mfma(
    const float* __restrict__ coords,
    const float* __restrict__ x_params,
    const float* __restrict__ t_params,
    const float* __restrict__ xW1, const float* __restrict__ xb1,
    const float* __restrict__ xW2, const float* __restrict__ xb2,
    const float* __restrict__ tW1, const float* __restrict__ tb1,
    const float* __restrict__ tW2, const float* __restrict__ tb2,
    const float* __restrict__ h0,  const float* __restrict__ gh0,
    const float* __restrict__ f_Wh, const float* __restrict__ f_bh,
    const float* __restrict__ f_Wz, const float* __restrict__ f_bz,
    const float* __restrict__ g_Wh, const float* __restrict__ g_bh,
    const float* __restrict__ g_Wz, const float* __restrict__ g_bz,
    const float* __restrict__ d_W,  const float* __restrict__ d_b,
    float* __restrict__ out)
{
    extern __shared__ char smem[];
    float* rawCfP = (float*)smem;         // [6][32] Cf (permuted, no ti term)
    float* sfz0p  = rawCfP + 192;         // [6][32] fz0 (permuted)
    float* sfz1p  = sfz0p + 192;          // [6][32] fz1 (permuted)
    float* sCgp   = sfz1p + 192;          // [6][32] Cg (permuted)
    float* sdWp   = sCgp + 192;           // [32] d_W (permuted)
    float* shx    = sdWp + 32;
    float* sht    = shx + 32;
    float* sex    = sht + 32;
    float* set_   = sex + 32;
    unsigned short* sImg = (unsigned short*)(set_ + 32); // 3 mats * 6 l * 2 s * 2 part * 512
    unsigned short* h0P  = sImg + 36864;  // [part][s][h][8]
    unsigned short* gh0P = h0P + 64;

    const int tid = threadIdx.x;
    const int b   = blockIdx.x >> 5;    // 32 blocks per batch
    const int ig  = blockIdx.x & 31;    // i-group: 8 i's per block

    // ================= PROLOGUE =================
    // P1: encoder stage 1 + A-frag image build
    if (tid < 32) {
        float a = xb1[tid];
        for (int k = 0; k < 16; ++k) a = fmaf(x_params[b * 16 + k], xW1[k * 32 + tid], a);
        shx[tid] = __sinf(a);
    } else if (tid < 64) {
        int d = tid - 32;
        float a = tb1[d];
        for (int k = 0; k < 8; ++k) a = fmaf(t_params[b * 8 + k], tW1[k * 32 + d], a);
        sht[d] = __sinf(a);
    }
    for (int idx = tid; idx < 9216; idx += 512) {
        int mat = idx / 3072, rem = idx % 3072;
        int l = rem >> 9, rem2 = rem & 511;
        int s = rem2 >> 8, lane = (rem2 >> 2) & 63, ip = rem2 & 3;
        int m = lane & 31, h = lane >> 5;
        int j0 = ip * 2;
        int c0 = Pmap(s, h, j0), c1 = Pmap(s, h, j0 + 1);
        float w0, w1;
        if (mat == 0)      { w0 = f_Wh[(l*32 + c0)*32 + m]; w1 = f_Wh[(l*32 + c1)*32 + m]; }
        else if (mat == 1) { w0 = g_Wh[(l*32 + c0)*32 + m]; w1 = g_Wh[(l*32 + c1)*32 + m]; }
        else               { w0 = g_Wz[(l*64 + c0)*32 + m]; w1 = g_Wz[(l*64 + c1)*32 + m]; }
        unsigned short hb0 = f2bf(w0), hb1 = f2bf(w1);
        unsigned short lb0 = f2bf(w0 - bf2f(hb0)), lb1 = f2bf(w1 - bf2f(hb1));
        int basehi = mat * 12288 + ((l * 2 + s) * 2 + 0) * 512 + lane * 8 + j0;
        sImg[basehi]       = hb0; sImg[basehi + 1]       = hb1;
        sImg[basehi + 512] = lb0; sImg[basehi + 512 + 1] = lb1;
    }
    __syncthreads();

    // P2: encoder stage 2 + fz0p/fz1p + dWp + h0/gh0 packed frags
    if (tid < 32) {
        float a = xb2[tid];
        for (int c = 0; c < 32; ++c) a = fmaf(shx[c], xW2[c * 32 + tid], a);
        sex[tid] = a;
    } else if (tid < 64) {
        int d = tid - 32;
        float a = tb2[d];
        for (int c = 0; c < 32; ++c) a = fmaf(sht[c], tW2[c * 32 + d], a);
        set_[d] = a;
    }
    if (tid < 192) {
        int l = tid >> 5, p = tid & 31, d = Qmap(p);
        sfz0p[tid] = f_Wz[(l * 34 + 0) * 32 + d];
        sfz1p[tid] = f_Wz[(l * 34 + 1) * 32 + d];
    }
    if (tid < 32) sdWp[tid] = d_W[Qmap(tid)];
    if (tid < 64) {
        int t = tid & 31;
        int s = (t >> 4) & 1, h = (t >> 3) & 1, j = t & 7;
        int c = Pmap(s, h, j);
        const float* src = (tid < 32) ? h0 : gh0;
        unsigned short* dst = (tid < 32) ? h0P : gh0P;
        float x = src[c];
        unsigned short hb = f2bf(x);
        dst[((0 * 2 + s) * 2 + h) * 8 + j] = hb;
        dst[((1 * 2 + s) * 2 + h) * 8 + j] = f2bf(x - bf2f(hb));
    }
    __syncthreads();

    // P3: Cf and Cg (permuted stores)
    if (tid < 192) {
        int l = tid >> 5, p = tid & 31, d = Qmap(p);
        float a = f_bh[l * 32 + d] + f_bz[l * 32 + d];
        for (int c = 0; c < 32; ++c) a = fmaf(set_[c], f_Wz[(l * 34 + 2 + c) * 32 + d], a);
        rawCfP[tid] = a;
        float g = g_bh[l * 32 + d] + g_bz[l * 32 + d];
        for (int c = 0; c < 32; ++c) g = fmaf(sex[c], g_Wz[(l * 64 + 32 + c) * 32 + d], g);
        sCgp[tid] = g;
    }
    __syncthreads();

    // ================= MAIN =================
    const int lane = tid & 63, wave = tid >> 6;
    const int i = ig * 8 + wave;
    const int e = lane & 31, hk = lane >> 5;
    const int pb = hk * 16;
    const float ti = coords[(b * 256 + i) * 2 + 1];

    const short8 h0B1h = *(const short8*)&h0P[((0*2+0)*2 + hk) * 8];
    const short8 h0B2h = *(const short8*)&h0P[((0*2+1)*2 + hk) * 8];
    const short8 h0B1l = *(const short8*)&h0P[((1*2+0)*2 + hk) * 8];
    const short8 h0B2l = *(const short8*)&h0P[((1*2+1)*2 + hk) * 8];
    const short8 g0B1h = *(const short8*)&gh0P[((0*2+0)*2 + hk) * 8];
    const short8 g0B2h = *(const short8*)&gh0P[((0*2+1)*2 + hk) * 8];
    const short8 g0B1l = *(const short8*)&gh0P[((1*2+0)*2 + hk) * 8];
    const short8 g0B2l = *(const short8*)&gh0P[((1*2+1)*2 + hk) * 8];

    const float db = d_b[0];

    for (int tile = 0; tile < 8; ++tile) {
        const int j = tile * 32 + e;
        const float xj = coords[(b * 256 + j) * 2];

        short8 hB1h = h0B1h, hB2h = h0B2h, hB1l = h0B1l, hB2l = h0B2l;
        floatx16 acc;

        // ---- f-scan ----
        for (int l = 0; l < NB; ++l) {
            const float* cf = &rawCfP[l * 32 + pb];
            const float* z0 = &sfz0p[l * 32 + pb];
            const float* z1 = &sfz1p[l * 32 + pb];
            #pragma unroll
            for (int r = 0; r < 16; ++r) acc[r] = fmaf(xj, z0[r], fmaf(ti, z1[r], cf[r]));
            const unsigned short* base = &sImg[0 * 12288 + (l * 4) * 512 + lane * 8];
            short8 ah0 = *(const short8*)(base);
            short8 al0 = *(const short8*)(base + 512);
            short8 ah1 = *(const short8*)(base + 1024);
            short8 al1 = *(const short8*)(base + 1536);
            acc = MFMA(ah0, hB1h, acc);
            acc = MFMA(ah0, hB1l, acc);
            acc = MFMA(al0, hB1h, acc);
            acc = MFMA(ah1, hB2h, acc);
            acc = MFMA(ah1, hB2l, acc);
            acc = MFMA(al1, hB2h, acc);
            sinsplit(acc, hB1h, hB1l, hB2h, hB2l);
        }

        // ---- g-scan ----
        short8 gB1h = g0B1h, gB2h = g0B2h, gB1l = g0B1l, gB2l = g0B2l;
        for (int l = 0; l < NB; ++l) {
            const float* cg = &sCgp[l * 32 + pb];
            #pragma unroll
            for (int r = 0; r < 16; ++r) acc[r] = cg[r];
            const unsigned short* bh = &sImg[1 * 12288 + (l * 4) * 512 + lane * 8];
            const unsigned short* bz = &sImg[2 * 12288 + (l * 4) * 512 + lane * 8];
            short8 wh_h0 = *(const short8*)(bh);
            short8 wh_l0 = *(const short8*)(bh + 512);
            short8 wh_h1 = *(const short8*)(bh + 1024);
            short8 wh_l1 = *(const short8*)(bh + 1536);
            short8 wz_h0 = *(const short8*)(bz);
            short8 wz_l0 = *(const short8*)(bz + 512);
            short8 wz_h1 = *(const short8*)(bz + 1024);
            short8 wz_l1 = *(const short8*)(bz + 1536);
            acc = MFMA(wh_h0, gB1h, acc);
            acc = MFMA(wh_h0, gB1l, acc);
            acc = MFMA(wh_l0, gB1h, acc);
            acc = MFMA(wz_h0, hB1h, acc);
            acc = MFMA(wz_h0, hB1l, acc);
            acc = MFMA(wz_l0, hB1h, acc);
            acc = MFMA(wh_h1, gB2h, acc);
            acc = MFMA(wh_h1, gB2l, acc);
            acc = MFMA(wh_l1, gB2h, acc);
            acc = MFMA(wz_h1, hB2h, acc);
            acc = MFMA(wz_h1, hB2l, acc);
            acc = MFMA(wz_l1, hB2h, acc);
            if (l < NB - 1) {
                sinsplit(acc, gB1h, gB1l, gB2h, gB2l);
            }
        }

        // ---- decode ----
        float u = 0.0f;
        #pragma unroll
        for (int r = 0; r < 16; ++r) u = fmaf(__sinf(acc[r]), sdWp[pb + r], u);
        u += __shfl_xor(u, 32);
        if (hk == 0) out[(b * 256 + i) * 256 + j] = u + db;
    }
}

extern "C" void kernel_launch(void* const* d_in, const int* in_sizes, int n_in,
                              void* d_out, int out_size, void* d_ws, size_t ws_size,
                              hipStream_t stream) {
    const float* coords   = (const float*)d_in[0];
    const float* x_params = (const float*)d_in[1];
    const float* t_params = (const float*)d_in[2];
    const float* xW1 = (const float*)d_in[3];
    const float* xb1 = (const float*)d_in[4];
    const float* xW2 = (const float*)d_in[5];
    const float* xb2 = (const float*)d_in[6];
    const float* tW1 = (const float*)d_in[7];
    const float* tb1 = (const float*)d_in[8];
    const float* tW2 = (const float*)d_in[9];
    const float* tb2 = (const float*)d_in[10];
    const float* h0  = (const float*)d_in[11];
    const float* gh0 = (const float*)d_in[12];
    const float* f_Wh = (const float*)d_in[13];
    const float* f_bh = (const float*)d_in[14];
    const float* f_Wz = (const float*)d_in[15];
    const float* f_bz = (const float*)d_in[16];
    const float* g_Wh = (const float*)d_in[17];
    const float* g_bh = (const float*)d_in[18];
    const float* g_Wz = (const float*)d_in[19];
    const float* g_bz = (const float*)d_in[20];
    const float* d_W  = (const float*)d_in[21];
    const float* d_b  = (const float*)d_in[22];

    hipFuncSetAttribute((const void*)sep_mfma,
                        hipFuncAttributeMaxDynamicSharedMemorySize, LDS_BYTES);

    // 16 batches * 32 i-groups = 512 blocks of 512 threads (8 waves, 1 i each)
    sep_mfma<<<512, 512, LDS_BYTES, stream>>>(
        coords, x_params, t_params, xW1, xb1, xW2, xb2, tW1, tb1, tW2, tb2,
        h0, gh0, f_Wh, f_bh, f_Wz, f_bz, g_Wh, g_bh, g_Wz, g_bz, d_W, d_b,
        (float*)d_out);
}

// Round 5
// 386.854 us; speedup vs baseline: 1.7675x; 1.7675x over previous
//
#include <hip/hip_runtime.h>

#define DIM 32
#define NB  6

typedef __attribute__((ext_vector_type(8)))  short short8;
typedef __attribute__((ext_vector_type(16))) float floatx16;

union S8I4 { short8 s; int i[4]; };

__device__ __forceinline__ unsigned short f2bf(float f) {
    unsigned u = __float_as_uint(f);
    return (unsigned short)((u + 0x7FFF + ((u >> 16) & 1)) >> 16);
}
__device__ __forceinline__ float bf2f(unsigned short b) {
    return __uint_as_float(((unsigned)b) << 16);
}
// B-frag slot (s,h,j) holds raw channel P; C/D reg (r,h) holds raw channel Q.
__device__ __forceinline__ int Pmap(int s, int h, int j) { return 16*s + 8*(j>>2) + 4*h + (j&3); }
__device__ __forceinline__ int Qmap(int p)               { int r = p & 15, h = p >> 4; return 8*(r>>2) + 4*h + (r&3); }

#define MFMA(a, b, c) __builtin_amdgcn_mfma_f32_32x32x16_bf16((a), (b), (c), 0, 0, 0)

// sin -> truncation hi/lo bf16 split, packed pairwise via v_perm_b32.
__device__ __forceinline__ void sinsplit(const floatx16& acc,
                                         short8& b1h, short8& b1l,
                                         short8& b2h, short8& b2l) {
    S8I4 nh1, nl1, nh2, nl2;
    #pragma unroll
    for (int q = 0; q < 4; ++q) {
        float s0 = __sinf(acc[2*q]), s1 = __sinf(acc[2*q+1]);
        unsigned a0 = __float_as_uint(s0), a1 = __float_as_uint(s1);
        nh1.i[q] = __builtin_amdgcn_perm(a1, a0, 0x07060302u);
        float l0 = s0 - __uint_as_float(a0 & 0xFFFF0000u);
        float l1 = s1 - __uint_as_float(a1 & 0xFFFF0000u);
        nl1.i[q] = __builtin_amdgcn_perm(__float_as_uint(l1), __float_as_uint(l0), 0x07060302u);
        float t0 = __sinf(acc[8+2*q]), t1 = __sinf(acc[8+2*q+1]);
        unsigned c0 = __float_as_uint(t0), c1 = __float_as_uint(t1);
        nh2.i[q] = __builtin_amdgcn_perm(c1, c0, 0x07060302u);
        float m0 = t0 - __uint_as_float(c0 & 0xFFFF0000u);
        float m1 = t1 - __uint_as_float(c1 & 0xFFFF0000u);
        nl2.i[q] = __builtin_amdgcn_perm(__float_as_uint(m1), __float_as_uint(m0), 0x07060302u);
    }
    b1h = nh1.s; b1l = nl1.s; b2h = nh2.s; b2l = nl2.s;
}

// LDS: 928 floats (3712 B) + 36992 shorts (73984 B) = 77696 B -> 2 blocks/CU.
#define LDS_BYTES 77696

// NOTE (measured R4): on this toolchain __launch_bounds__ arg2 acts as min
// BLOCKS/CU (CUDA semantics): (512,4) forced a 64-VGPR cap -> 1.6 GB scratch
// spill. (512,2) = 2 blocks/CU = 16 waves/CU = 128-VGPR cap, matching the
// 2-blocks/CU LDS limit.
__global__ __launch_bounds__(512, 2) void sep_mfma(
    const float* __restrict__ coords,
    const float* __restrict__ x_params,
    const float* __restrict__ t_params,
    const float* __restrict__ xW1, const float* __restrict__ xb1,
    const float* __restrict__ xW2, const float* __restrict__ xb2,
    const float* __restrict__ tW1, const float* __restrict__ tb1,
    const float* __restrict__ tW2, const float* __restrict__ tb2,
    const float* __restrict__ h0,  const float* __restrict__ gh0,
    const float* __restrict__ f_Wh, const float* __restrict__ f_bh,
    const float* __restrict__ f_Wz, const float* __restrict__ f_bz,
    const float* __restrict__ g_Wh, const float* __restrict__ g_bh,
    const float* __restrict__ g_Wz, const float* __restrict__ g_bz,
    const float* __restrict__ d_W,  const float* __restrict__ d_b,
    float* __restrict__ out)
{
    extern __shared__ char smem[];
    float* rawCfP = (float*)smem;         // [6][32] Cf (permuted, no ti term)
    float* sfz0p  = rawCfP + 192;         // [6][32] fz0 (permuted)
    float* sfz1p  = sfz0p + 192;          // [6][32] fz1 (permuted)
    float* sCgp   = sfz1p + 192;          // [6][32] Cg (permuted)
    float* sdWp   = sCgp + 192;           // [32] d_W (permuted)
    float* shx    = sdWp + 32;
    float* sht    = shx + 32;
    float* sex    = sht + 32;
    float* set_   = sex + 32;
    unsigned short* sImg = (unsigned short*)(set_ + 32); // 3 mats * 6 l * 2 s * 2 part * 512
    unsigned short* h0P  = sImg + 36864;  // [part][s][h][8]
    unsigned short* gh0P = h0P + 64;

    const int tid = threadIdx.x;
    const int b   = blockIdx.x >> 5;    // 32 blocks per batch
    const int ig  = blockIdx.x & 31;    // i-group: 8 i's per block

    // ================= PROLOGUE =================
    // P1: encoder stage 1 + A-frag image build
    if (tid < 32) {
        float a = xb1[tid];
        for (int k = 0; k < 16; ++k) a = fmaf(x_params[b * 16 + k], xW1[k * 32 + tid], a);
        shx[tid] = __sinf(a);
    } else if (tid < 64) {
        int d = tid - 32;
        float a = tb1[d];
        for (int k = 0; k < 8; ++k) a = fmaf(t_params[b * 8 + k], tW1[k * 32 + d], a);
        sht[d] = __sinf(a);
    }
    for (int idx = tid; idx < 9216; idx += 512) {
        int mat = idx / 3072, rem = idx % 3072;
        int l = rem >> 9, rem2 = rem & 511;
        int s = rem2 >> 8, lane = (rem2 >> 2) & 63, ip = rem2 & 3;
        int m = lane & 31, h = lane >> 5;
        int j0 = ip * 2;
        int c0 = Pmap(s, h, j0), c1 = Pmap(s, h, j0 + 1);
        float w0, w1;
        if (mat == 0)      { w0 = f_Wh[(l*32 + c0)*32 + m]; w1 = f_Wh[(l*32 + c1)*32 + m]; }
        else if (mat == 1) { w0 = g_Wh[(l*32 + c0)*32 + m]; w1 = g_Wh[(l*32 + c1)*32 + m]; }
        else               { w0 = g_Wz[(l*64 + c0)*32 + m]; w1 = g_Wz[(l*64 + c1)*32 + m]; }
        unsigned short hb0 = f2bf(w0), hb1 = f2bf(w1);
        unsigned short lb0 = f2bf(w0 - bf2f(hb0)), lb1 = f2bf(w1 - bf2f(hb1));
        int basehi = mat * 12288 + ((l * 2 + s) * 2 + 0) * 512 + lane * 8 + j0;
        sImg[basehi]       = hb0; sImg[basehi + 1]       = hb1;
        sImg[basehi + 512] = lb0; sImg[basehi + 512 + 1] = lb1;
    }
    __syncthreads();

    // P2: encoder stage 2 + fz0p/fz1p + dWp + h0/gh0 packed frags
    if (tid < 32) {
        float a = xb2[tid];
        for (int c = 0; c < 32; ++c) a = fmaf(shx[c], xW2[c * 32 + tid], a);
        sex[tid] = a;
    } else if (tid < 64) {
        int d = tid - 32;
        float a = tb2[d];
        for (int c = 0; c < 32; ++c) a = fmaf(sht[c], tW2[c * 32 + d], a);
        set_[d] = a;
    }
    if (tid < 192) {
        int l = tid >> 5, p = tid & 31, d = Qmap(p);
        sfz0p[tid] = f_Wz[(l * 34 + 0) * 32 + d];
        sfz1p[tid] = f_Wz[(l * 34 + 1) * 32 + d];
    }
    if (tid < 32) sdWp[tid] = d_W[Qmap(tid)];
    if (tid < 64) {
        int t = tid & 31;
        int s = (t >> 4) & 1, h = (t >> 3) & 1, j = t & 7;
        int c = Pmap(s, h, j);
        const float* src = (tid < 32) ? h0 : gh0;
        unsigned short* dst = (tid < 32) ? h0P : gh0P;
        float x = src[c];
        unsigned short hb = f2bf(x);
        dst[((0 * 2 + s) * 2 + h) * 8 + j] = hb;
        dst[((1 * 2 + s) * 2 + h) * 8 + j] = f2bf(x - bf2f(hb));
    }
    __syncthreads();

    // P3: Cf and Cg (permuted stores)
    if (tid < 192) {
        int l = tid >> 5, p = tid & 31, d = Qmap(p);
        float a = f_bh[l * 32 + d] + f_bz[l * 32 + d];
        for (int c = 0; c < 32; ++c) a = fmaf(set_[c], f_Wz[(l * 34 + 2 + c) * 32 + d], a);
        rawCfP[tid] = a;
        float g = g_bh[l * 32 + d] + g_bz[l * 32 + d];
        for (int c = 0; c < 32; ++c) g = fmaf(sex[c], g_Wz[(l * 64 + 32 + c) * 32 + d], g);
        sCgp[tid] = g;
    }
    __syncthreads();

    // ================= MAIN =================
    const int lane = tid & 63, wave = tid >> 6;
    const int i = ig * 8 + wave;
    const int e = lane & 31, hk = lane >> 5;
    const int pb = hk * 16;
    const float ti = coords[(b * 256 + i) * 2 + 1];

    const short8 h0B1h = *(const short8*)&h0P[((0*2+0)*2 + hk) * 8];
    const short8 h0B2h = *(const short8*)&h0P[((0*2+1)*2 + hk) * 8];
    const short8 h0B1l = *(const short8*)&h0P[((1*2+0)*2 + hk) * 8];
    const short8 h0B2l = *(const short8*)&h0P[((1*2+1)*2 + hk) * 8];
    const short8 g0B1h = *(const short8*)&gh0P[((0*2+0)*2 + hk) * 8];
    const short8 g0B2h = *(const short8*)&gh0P[((0*2+1)*2 + hk) * 8];
    const short8 g0B1l = *(const short8*)&gh0P[((1*2+0)*2 + hk) * 8];
    const short8 g0B2l = *(const short8*)&gh0P[((1*2+1)*2 + hk) * 8];

    const float db = d_b[0];

    for (int tile = 0; tile < 8; ++tile) {
        const int j = tile * 32 + e;
        const float xj = coords[(b * 256 + j) * 2];

        short8 hB1h = h0B1h, hB2h = h0B2h, hB1l = h0B1l, hB2l = h0B2l;
        floatx16 acc;

        // ---- f-scan ----
        for (int l = 0; l < NB; ++l) {
            const float* cf = &rawCfP[l * 32 + pb];
            const float* z0 = &sfz0p[l * 32 + pb];
            const float* z1 = &sfz1p[l * 32 + pb];
            #pragma unroll
            for (int r = 0; r < 16; ++r) acc[r] = fmaf(xj, z0[r], fmaf(ti, z1[r], cf[r]));
            const unsigned short* base = &sImg[0 * 12288 + (l * 4) * 512 + lane * 8];
            short8 ah0 = *(const short8*)(base);
            short8 al0 = *(const short8*)(base + 512);
            short8 ah1 = *(const short8*)(base + 1024);
            short8 al1 = *(const short8*)(base + 1536);
            acc = MFMA(ah0, hB1h, acc);
            acc = MFMA(ah0, hB1l, acc);
            acc = MFMA(al0, hB1h, acc);
            acc = MFMA(ah1, hB2h, acc);
            acc = MFMA(ah1, hB2l, acc);
            acc = MFMA(al1, hB2h, acc);
            sinsplit(acc, hB1h, hB1l, hB2h, hB2l);
        }

        // ---- g-scan ----
        short8 gB1h = g0B1h, gB2h = g0B2h, gB1l = g0B1l, gB2l = g0B2l;
        for (int l = 0; l < NB; ++l) {
            const float* cg = &sCgp[l * 32 + pb];
            #pragma unroll
            for (int r = 0; r < 16; ++r) acc[r] = cg[r];
            const unsigned short* bh = &sImg[1 * 12288 + (l * 4) * 512 + lane * 8];
            const unsigned short* bz = &sImg[2 * 12288 + (l * 4) * 512 + lane * 8];
            short8 wh_h0 = *(const short8*)(bh);
            short8 wh_l0 = *(const short8*)(bh + 512);
            short8 wh_h1 = *(const short8*)(bh + 1024);
            short8 wh_l1 = *(const short8*)(bh + 1536);
            short8 wz_h0 = *(const short8*)(bz);
            short8 wz_l0 = *(const short8*)(bz + 512);
            short8 wz_h1 = *(const short8*)(bz + 1024);
            short8 wz_l1 = *(const short8*)(bz + 1536);
            acc = MFMA(wh_h0, gB1h, acc);
            acc = MFMA(wh_h0, gB1l, acc);
            acc = MFMA(wh_l0, gB1h, acc);
            acc = MFMA(wz_h0, hB1h, acc);
            acc = MFMA(wz_h0, hB1l, acc);
            acc = MFMA(wz_l0, hB1h, acc);
            acc = MFMA(wh_h1, gB2h, acc);
            acc = MFMA(wh_h1, gB2l, acc);
            acc = MFMA(wh_l1, gB2h, acc);
            acc = MFMA(wz_h1, hB2h, acc);
            acc = MFMA(wz_h1, hB2l, acc);
            acc = MFMA(wz_l1, hB2h, acc);
            if (l < NB - 1) {
                sinsplit(acc, gB1h, gB1l, gB2h, gB2l);
            }
        }

        // ---- decode ----
        float u = 0.0f;
        #pragma unroll
        for (int r = 0; r < 16; ++r) u = fmaf(__sinf(acc[r]), sdWp[pb + r], u);
        u += __shfl_xor(u, 32);
        if (hk == 0) out[(b * 256 + i) * 256 + j] = u + db;
    }
}

extern "C" void kernel_launch(void* const* d_in, const int* in_sizes, int n_in,
                              void* d_out, int out_size, void* d_ws, size_t ws_size,
                              hipStream_t stream) {
    const float* coords   = (const float*)d_in[0];
    const float* x_params = (const float*)d_in[1];
    const float* t_params = (const float*)d_in[2];
    const float* xW1 = (const float*)d_in[3];
    const float* xb1 = (const float*)d_in[4];
    const float* xW2 = (const float*)d_in[5];
    const float* xb2 = (const float*)d_in[6];
    const float* tW1 = (const float*)d_in[7];
    const float* tb1 = (const float*)d_in[8];
    const float* tW2 = (const float*)d_in[9];
    const float* tb2 = (const float*)d_in[10];
    const float* h0  = (const float*)d_in[11];
    const float* gh0 = (const float*)d_in[12];
    const float* f_Wh = (const float*)d_in[13];
    const float* f_bh = (const float*)d_in[14];
    const float* f_Wz = (const float*)d_in[15];
    const float* f_bz = (const float*)d_in[16];
    const float* g_Wh = (const float*)d_in[17];
    const float* g_bh = (const float*)d_in[18];
    const float* g_Wz = (const float*)d_in[19];
    const float* g_bz = (const float*)d_in[20];
    const float* d_W  = (const float*)d_in[21];
    const float* d_b  = (const float*)d_in[22];

    hipFuncSetAttribute((const void*)sep_mfma,
                        hipFuncAttributeMaxDynamicSharedMemorySize, LDS_BYTES);

    // 16 batches * 32 i-groups = 512 blocks of 512 threads (8 waves, 1 i each)
    sep_mfma<<<512, 512, LDS_BYTES, stream>>>(
        coords, x_params, t_params, xW1, xb1, xW2, xb2, tW1, tb1, tW2, tb2,
        h0, gh0, f_Wh, f_bh, f_Wz, f_bz, g_Wh, g_bh, g_Wz, g_bz, d_W, d_b,
        (float*)d_out);
}

// Round 6
// 227.406 us; speedup vs baseline: 3.0068x; 1.7012x over previous
//
#include <hip/hip_runtime.h>

#define DIM 32
#define NB  6

typedef __attribute__((ext_vector_type(8)))  short short8;
typedef __attribute__((ext_vector_type(16))) float floatx16;

union S8I4 { short8 s; int i[4]; };

__device__ __forceinline__ unsigned short f2bf(float f) {
    unsigned u = __float_as_uint(f);
    return (unsigned short)((u + 0x7FFF + ((u >> 16) & 1)) >> 16);
}
__device__ __forceinline__ float bf2f(unsigned short b) {
    return __uint_as_float(((unsigned)b) << 16);
}
// B-frag slot (s,h,j) holds raw channel P; C/D reg (r,h) holds raw channel Q.
__device__ __forceinline__ int Pmap(int s, int h, int j) { return 16*s + 8*(j>>2) + 4*h + (j&3); }
__device__ __forceinline__ int Qmap(int p)               { int r = p & 15, h = p >> 4; return 8*(r>>2) + 4*h + (r&3); }

#define MFMA(a, b, c) __builtin_amdgcn_mfma_f32_32x32x16_bf16((a), (b), (c), 0, 0, 0)

// sin -> truncation hi/lo bf16 split, packed pairwise via v_perm_b32.
__device__ __forceinline__ void sinsplit(const floatx16& acc,
                                         short8& b1h, short8& b1l,
                                         short8& b2h, short8& b2l) {
    S8I4 nh1, nl1, nh2, nl2;
    #pragma unroll
    for (int q = 0; q < 4; ++q) {
        float s0 = __sinf(acc[2*q]), s1 = __sinf(acc[2*q+1]);
        unsigned a0 = __float_as_uint(s0), a1 = __float_as_uint(s1);
        nh1.i[q] = __builtin_amdgcn_perm(a1, a0, 0x07060302u);
        float l0 = s0 - __uint_as_float(a0 & 0xFFFF0000u);
        float l1 = s1 - __uint_as_float(a1 & 0xFFFF0000u);
        nl1.i[q] = __builtin_amdgcn_perm(__float_as_uint(l1), __float_as_uint(l0), 0x07060302u);
        float t0 = __sinf(acc[8+2*q]), t1 = __sinf(acc[8+2*q+1]);
        unsigned c0 = __float_as_uint(t0), c1 = __float_as_uint(t1);
        nh2.i[q] = __builtin_amdgcn_perm(c1, c0, 0x07060302u);
        float m0 = t0 - __uint_as_float(c0 & 0xFFFF0000u);
        float m1 = t1 - __uint_as_float(c1 & 0xFFFF0000u);
        nl2.i[q] = __builtin_amdgcn_perm(__float_as_uint(m1), __float_as_uint(m0), 0x07060302u);
    }
    b1h = nh1.s; b1l = nl1.s; b2h = nh2.s; b2l = nl2.s;
}

// LDS: 928 floats (3712 B) + 36992 shorts (73984 B) = 77696 B -> 2 blocks/CU.
#define LDS_BYTES 77696

// NOTE (measured R4/R5): __launch_bounds__ arg2 acts as min BLOCKS/CU here.
// (512,2) -> 128-VGPR cap. Body restructured so peak live-set fits 128:
// initial frags reloaded from LDS per tile, weight frags loaded in halves
// (sched_barrier pins the halves), tile loop not unrolled.
__global__ __launch_bounds__(512, 2) void sep_mfma(
    const float* __restrict__ coords,
    const float* __restrict__ x_params,
    const float* __restrict__ t_params,
    const float* __restrict__ xW1, const float* __restrict__ xb1,
    const float* __restrict__ xW2, const float* __restrict__ xb2,
    const float* __restrict__ tW1, const float* __restrict__ tb1,
    const float* __restrict__ tW2, const float* __restrict__ tb2,
    const float* __restrict__ h0,  const float* __restrict__ gh0,
    const float* __restrict__ f_Wh, const float* __restrict__ f_bh,
    const float* __restrict__ f_Wz, const float* __restrict__ f_bz,
    const float* __restrict__ g_Wh, const float* __restrict__ g_bh,
    const float* __restrict__ g_Wz, const float* __restrict__ g_bz,
    const float* __restrict__ d_W,  const float* __restrict__ d_b,
    float* __restrict__ out)
{
    extern __shared__ char smem[];
    float* rawCfP = (float*)smem;         // [6][32] Cf (permuted, no ti term)
    float* sfz0p  = rawCfP + 192;         // [6][32] fz0 (permuted)
    float* sfz1p  = sfz0p + 192;          // [6][32] fz1 (permuted)
    float* sCgp   = sfz1p + 192;          // [6][32] Cg (permuted)
    float* sdWp   = sCgp + 192;           // [32] d_W (permuted)
    float* shx    = sdWp + 32;
    float* sht    = shx + 32;
    float* sex    = sht + 32;
    float* set_   = sex + 32;
    unsigned short* sImg = (unsigned short*)(set_ + 32); // 3 mats * 6 l * 2 s * 2 part * 512
    unsigned short* h0P  = sImg + 36864;  // [part][s][h][8]
    unsigned short* gh0P = h0P + 64;

    const int tid = threadIdx.x;
    const int b   = blockIdx.x >> 5;    // 32 blocks per batch
    const int ig  = blockIdx.x & 31;    // i-group: 8 i's per block

    // ================= PROLOGUE =================
    // P1: encoder stage 1 + A-frag image build
    if (tid < 32) {
        float a = xb1[tid];
        for (int k = 0; k < 16; ++k) a = fmaf(x_params[b * 16 + k], xW1[k * 32 + tid], a);
        shx[tid] = __sinf(a);
    } else if (tid < 64) {
        int d = tid - 32;
        float a = tb1[d];
        for (int k = 0; k < 8; ++k) a = fmaf(t_params[b * 8 + k], tW1[k * 32 + d], a);
        sht[d] = __sinf(a);
    }
    for (int idx = tid; idx < 9216; idx += 512) {
        int mat = idx / 3072, rem = idx % 3072;
        int l = rem >> 9, rem2 = rem & 511;
        int s = rem2 >> 8, lane = (rem2 >> 2) & 63, ip = rem2 & 3;
        int m = lane & 31, h = lane >> 5;
        int j0 = ip * 2;
        int c0 = Pmap(s, h, j0), c1 = Pmap(s, h, j0 + 1);
        float w0, w1;
        if (mat == 0)      { w0 = f_Wh[(l*32 + c0)*32 + m]; w1 = f_Wh[(l*32 + c1)*32 + m]; }
        else if (mat == 1) { w0 = g_Wh[(l*32 + c0)*32 + m]; w1 = g_Wh[(l*32 + c1)*32 + m]; }
        else               { w0 = g_Wz[(l*64 + c0)*32 + m]; w1 = g_Wz[(l*64 + c1)*32 + m]; }
        unsigned short hb0 = f2bf(w0), hb1 = f2bf(w1);
        unsigned short lb0 = f2bf(w0 - bf2f(hb0)), lb1 = f2bf(w1 - bf2f(hb1));
        int basehi = mat * 12288 + ((l * 2 + s) * 2 + 0) * 512 + lane * 8 + j0;
        sImg[basehi]       = hb0; sImg[basehi + 1]       = hb1;
        sImg[basehi + 512] = lb0; sImg[basehi + 512 + 1] = lb1;
    }
    __syncthreads();

    // P2: encoder stage 2 + fz0p/fz1p + dWp + h0/gh0 packed frags
    if (tid < 32) {
        float a = xb2[tid];
        for (int c = 0; c < 32; ++c) a = fmaf(shx[c], xW2[c * 32 + tid], a);
        sex[tid] = a;
    } else if (tid < 64) {
        int d = tid - 32;
        float a = tb2[d];
        for (int c = 0; c < 32; ++c) a = fmaf(sht[c], tW2[c * 32 + d], a);
        set_[d] = a;
    }
    if (tid < 192) {
        int l = tid >> 5, p = tid & 31, d = Qmap(p);
        sfz0p[tid] = f_Wz[(l * 34 + 0) * 32 + d];
        sfz1p[tid] = f_Wz[(l * 34 + 1) * 32 + d];
    }
    if (tid < 32) sdWp[tid] = d_W[Qmap(tid)];
    if (tid < 64) {
        int t = tid & 31;
        int s = (t >> 4) & 1, h = (t >> 3) & 1, j = t & 7;
        int c = Pmap(s, h, j);
        const float* src = (tid < 32) ? h0 : gh0;
        unsigned short* dst = (tid < 32) ? h0P : gh0P;
        float x = src[c];
        unsigned short hb = f2bf(x);
        dst[((0 * 2 + s) * 2 + h) * 8 + j] = hb;
        dst[((1 * 2 + s) * 2 + h) * 8 + j] = f2bf(x - bf2f(hb));
    }
    __syncthreads();

    // P3: Cf and Cg (permuted stores)
    if (tid < 192) {
        int l = tid >> 5, p = tid & 31, d = Qmap(p);
        float a = f_bh[l * 32 + d] + f_bz[l * 32 + d];
        for (int c = 0; c < 32; ++c) a = fmaf(set_[c], f_Wz[(l * 34 + 2 + c) * 32 + d], a);
        rawCfP[tid] = a;
        float g = g_bh[l * 32 + d] + g_bz[l * 32 + d];
        for (int c = 0; c < 32; ++c) g = fmaf(sex[c], g_Wz[(l * 64 + 32 + c) * 32 + d], g);
        sCgp[tid] = g;
    }
    __syncthreads();

    // ================= MAIN =================
    const int lane = tid & 63, wave = tid >> 6;
    const int i = ig * 8 + wave;
    const int e = lane & 31, hk = lane >> 5;
    const int pb = hk * 16;
    const float ti = coords[(b * 256 + i) * 2 + 1];
    const float db = d_b[0];

    #pragma unroll 1
    for (int tile = 0; tile < 8; ++tile) {
        const int j = tile * 32 + e;
        const float xj = coords[(b * 256 + j) * 2];

        // reload initial fragments from LDS (keeps them out of long-lived regs)
        short8 hB1h = *(const short8*)&h0P[((0*2+0)*2 + hk) * 8];
        short8 hB2h = *(const short8*)&h0P[((0*2+1)*2 + hk) * 8];
        short8 hB1l = *(const short8*)&h0P[((1*2+0)*2 + hk) * 8];
        short8 hB2l = *(const short8*)&h0P[((1*2+1)*2 + hk) * 8];
        floatx16 acc;

        // ---- f-scan ----
        for (int l = 0; l < NB; ++l) {
            const float* cf = &rawCfP[l * 32 + pb];
            const float* z0 = &sfz0p[l * 32 + pb];
            const float* z1 = &sfz1p[l * 32 + pb];
            #pragma unroll
            for (int r = 0; r < 16; ++r) acc[r] = fmaf(xj, z0[r], fmaf(ti, z1[r], cf[r]));
            const unsigned short* base = &sImg[0 * 12288 + (l * 4) * 512 + lane * 8];
            {
                short8 ah0 = *(const short8*)(base);
                short8 al0 = *(const short8*)(base + 512);
                acc = MFMA(ah0, hB1h, acc);
                acc = MFMA(ah0, hB1l, acc);
                acc = MFMA(al0, hB1h, acc);
            }
            __builtin_amdgcn_sched_barrier(0);
            {
                short8 ah1 = *(const short8*)(base + 1024);
                short8 al1 = *(const short8*)(base + 1536);
                acc = MFMA(ah1, hB2h, acc);
                acc = MFMA(ah1, hB2l, acc);
                acc = MFMA(al1, hB2h, acc);
            }
            sinsplit(acc, hB1h, hB1l, hB2h, hB2l);
        }

        // ---- g-scan ----
        short8 gB1h = *(const short8*)&gh0P[((0*2+0)*2 + hk) * 8];
        short8 gB2h = *(const short8*)&gh0P[((0*2+1)*2 + hk) * 8];
        short8 gB1l = *(const short8*)&gh0P[((1*2+0)*2 + hk) * 8];
        short8 gB2l = *(const short8*)&gh0P[((1*2+1)*2 + hk) * 8];
        for (int l = 0; l < NB; ++l) {
            const float* cg = &sCgp[l * 32 + pb];
            #pragma unroll
            for (int r = 0; r < 16; ++r) acc[r] = cg[r];
            const unsigned short* bh = &sImg[1 * 12288 + (l * 4) * 512 + lane * 8];
            const unsigned short* bz = &sImg[2 * 12288 + (l * 4) * 512 + lane * 8];
            {
                short8 wh_h0 = *(const short8*)(bh);
                short8 wh_l0 = *(const short8*)(bh + 512);
                short8 wz_h0 = *(const short8*)(bz);
                short8 wz_l0 = *(const short8*)(bz + 512);
                acc = MFMA(wh_h0, gB1h, acc);
                acc = MFMA(wh_h0, gB1l, acc);
                acc = MFMA(wh_l0, gB1h, acc);
                acc = MFMA(wz_h0, hB1h, acc);
                acc = MFMA(wz_h0, hB1l, acc);
                acc = MFMA(wz_l0, hB1h, acc);
            }
            __builtin_amdgcn_sched_barrier(0);
            {
                short8 wh_h1 = *(const short8*)(bh + 1024);
                short8 wh_l1 = *(const short8*)(bh + 1536);
                short8 wz_h1 = *(const short8*)(bz + 1024);
                short8 wz_l1 = *(const short8*)(bz + 1536);
                acc = MFMA(wh_h1, gB2h, acc);
                acc = MFMA(wh_h1, gB2l, acc);
                acc = MFMA(wh_l1, gB2h, acc);
                acc = MFMA(wz_h1, hB2h, acc);
                acc = MFMA(wz_h1, hB2l, acc);
                acc = MFMA(wz_l1, hB2h, acc);
            }
            if (l < NB - 1) {
                sinsplit(acc, gB1h, gB1l, gB2h, gB2l);
            }
        }

        // ---- decode ----
        float u = 0.0f;
        #pragma unroll
        for (int r = 0; r < 16; ++r) u = fmaf(__sinf(acc[r]), sdWp[pb + r], u);
        u += __shfl_xor(u, 32);
        if (hk == 0) out[(b * 256 + i) * 256 + j] = u + db;
    }
}

extern "C" void kernel_launch(void* const* d_in, const int* in_sizes, int n_in,
                              void* d_out, int out_size, void* d_ws, size_t ws_size,
                              hipStream_t stream) {
    const float* coords   = (const float*)d_in[0];
    const float* x_params = (const float*)d_in[1];
    const float* t_params = (const float*)d_in[2];
    const float* xW1 = (const float*)d_in[3];
    const float* xb1 = (const float*)d_in[4];
    const float* xW2 = (const float*)d_in[5];
    const float* xb2 = (const float*)d_in[6];
    const float* tW1 = (const float*)d_in[7];
    const float* tb1 = (const float*)d_in[8];
    const float* tW2 = (const float*)d_in[9];
    const float* tb2 = (const float*)d_in[10];
    const float* h0  = (const float*)d_in[11];
    const float* gh0 = (const float*)d_in[12];
    const float* f_Wh = (const float*)d_in[13];
    const float* f_bh = (const float*)d_in[14];
    const float* f_Wz = (const float*)d_in[15];
    const float* f_bz = (const float*)d_in[16];
    const float* g_Wh = (const float*)d_in[17];
    const float* g_bh = (const float*)d_in[18];
    const float* g_Wz = (const float*)d_in[19];
    const float* g_bz = (const float*)d_in[20];
    const float* d_W  = (const float*)d_in[21];
    const float* d_b  = (const float*)d_in[22];

    hipFuncSetAttribute((const void*)sep_mfma,
                        hipFuncAttributeMaxDynamicSharedMemorySize, LDS_BYTES);

    // 16 batches * 32 i-groups = 512 blocks of 512 threads (8 waves, 1 i each)
    sep_mfma<<<512, 512, LDS_BYTES, stream>>>(
        coords, x_params, t_params, xW1, xb1, xW2, xb2, tW1, tb1, tW2, tb2,
        h0, gh0, f_Wh, f_bh, f_Wz, f_bz, g_Wh, g_bh, g_Wz, g_bz, d_W, d_b,
        (float*)d_out);
}

// Round 7
// 200.934 us; speedup vs baseline: 3.4030x; 1.1317x over previous
//
#include <hip/hip_runtime.h>

#define DIM 32
#define NB  6
#define INV2PI 0.15915494309189535f

typedef __attribute__((ext_vector_type(8)))  short short8;
typedef __attribute__((ext_vector_type(16))) float floatx16;

union S8I4 { short8 s; int i[4]; };

__device__ __forceinline__ unsigned short f2bf(float f) {   // RNE
    unsigned u = __float_as_uint(f);
    return (unsigned short)((u + 0x7FFF + ((u >> 16) & 1)) >> 16);
}
__device__ __forceinline__ float bf2f(unsigned short b) {
    return __uint_as_float(((unsigned)b) << 16);
}
// B-frag slot (s,h,j) holds raw channel P; C/D reg (r,h) holds raw channel Q.
__device__ __forceinline__ int Pmap(int s, int h, int j) { return 16*s + 8*(j>>2) + 4*h + (j&3); }
__device__ __forceinline__ int Qmap(int p)               { int r = p & 15, h = p >> 4; return 8*(r>>2) + 4*h + (r&3); }

#define MFMA(a, b, c) __builtin_amdgcn_mfma_f32_32x32x16_bf16((a), (b), (c), 0, 0, 0)

// acc is in revolution domain (weights prescaled by 1/2pi):
// raw v_sin, then truncation hi/lo bf16 split packed via v_perm.
__device__ __forceinline__ void sinsplit(const floatx16& acc,
                                         short8& b1h, short8& b1l,
                                         short8& b2h, short8& b2l) {
    S8I4 nh1, nl1, nh2, nl2;
    #pragma unroll
    for (int q = 0; q < 4; ++q) {
        float s0 = __builtin_amdgcn_sinf(acc[2*q]), s1 = __builtin_amdgcn_sinf(acc[2*q+1]);
        unsigned a0 = __float_as_uint(s0), a1 = __float_as_uint(s1);
        nh1.i[q] = __builtin_amdgcn_perm(a1, a0, 0x07060302u);
        float l0 = s0 - __uint_as_float(a0 & 0xFFFF0000u);
        float l1 = s1 - __uint_as_float(a1 & 0xFFFF0000u);
        nl1.i[q] = __builtin_amdgcn_perm(__float_as_uint(l1), __float_as_uint(l0), 0x07060302u);
        float t0 = __builtin_amdgcn_sinf(acc[8+2*q]), t1 = __builtin_amdgcn_sinf(acc[8+2*q+1]);
        unsigned c0 = __float_as_uint(t0), c1 = __float_as_uint(t1);
        nh2.i[q] = __builtin_amdgcn_perm(c1, c0, 0x07060302u);
        float m0 = t0 - __uint_as_float(c0 & 0xFFFF0000u);
        float m1 = t1 - __uint_as_float(c1 & 0xFFFF0000u);
        nl2.i[q] = __builtin_amdgcn_perm(__float_as_uint(m1), __float_as_uint(m0), 0x07060302u);
    }
    b1h = nh1.s; b1l = nl1.s; b2h = nh2.s; b2l = nl2.s;
}

// LDS: 2464 floats (9856 B) + 18432 shorts (36864 B) = 46720 B -> 3 blocks/CU.
#define LDS_BYTES 46720

// NOTE (measured R4/R5): __launch_bounds__ arg2 = min BLOCKS/CU on this
// toolchain. (512,3) -> 85-VGPR cap; est. peak live-set ~76-83.
__global__ __launch_bounds__(512, 3) void sep_mfma(
    const float* __restrict__ coords,
    const float* __restrict__ x_params,
    const float* __restrict__ t_params,
    const float* __restrict__ xW1, const float* __restrict__ xb1,
    const float* __restrict__ xW2, const float* __restrict__ xb2,
    const float* __restrict__ tW1, const float* __restrict__ tb1,
    const float* __restrict__ tW2, const float* __restrict__ tb2,
    const float* __restrict__ h0,  const float* __restrict__ gh0,
    const float* __restrict__ f_Wh, const float* __restrict__ f_bh,
    const float* __restrict__ f_Wz, const float* __restrict__ f_bz,
    const float* __restrict__ g_Wh, const float* __restrict__ g_bh,
    const float* __restrict__ g_Wz, const float* __restrict__ g_bz,
    const float* __restrict__ d_W,  const float* __restrict__ d_b,
    float* __restrict__ out)
{
    extern __shared__ char smem[];
    float* sCfi   = (float*)smem;            // [8 waves][6][32] (Cf + ti*fz1)/2pi
    float* sfz0p  = sCfi + 1536;             // [6][32] fz0/2pi (permuted)
    float* sfz1p  = sfz0p + 192;             // [6][32] fz1/2pi (permuted)
    float* sCgp   = sfz1p + 192;             // [6][32] Cg/2pi (permuted, +gh0 fold at l=0)
    float* sdWp   = sCgp + 192;              // [32] d_W (permuted, NOT scaled)
    float* shx    = sdWp + 32;
    float* sht    = shx + 32;
    float* sex    = sht + 32;
    float* set_   = sex + 32;
    float* rawCfP = set_ + 32;               // [6][32] Cf/2pi (permuted, no ti term, +h0 fold at l=0)
    unsigned short* sImg = (unsigned short*)(rawCfP + 192); // [3 mats][6 l][2 s][512] hi-only RNE bf16, prescaled

    const int tid = threadIdx.x;
    const int b   = blockIdx.x >> 6;          // 64 blocks per batch
    const int ig  = (blockIdx.x >> 1) & 31;   // i-group: 8 i's per block
    const int jg  = blockIdx.x & 1;           // j-half: 4 tiles per block

    // ================= PROLOGUE =================
    // P1: encoder stage 1 + A-frag image build (hi-only, RNE, prescaled)
    if (tid < 32) {
        float a = xb1[tid];
        for (int k = 0; k < 16; ++k) a = fmaf(x_params[b * 16 + k], xW1[k * 32 + tid], a);
        shx[tid] = __sinf(a);
    } else if (tid < 64) {
        int d = tid - 32;
        float a = tb1[d];
        for (int k = 0; k < 8; ++k) a = fmaf(t_params[b * 8 + k], tW1[k * 32 + d], a);
        sht[d] = __sinf(a);
    }
    for (int idx = tid; idx < 18432; idx += 512) {
        int mat = idx / 6144, rem = idx % 6144;
        int l = rem >> 10, rem2 = rem & 1023;
        int s = rem2 >> 9, t = rem2 & 511;
        int lane = t >> 3, jj = t & 7;
        int m = lane & 31, hg = lane >> 5;
        int c = Pmap(s, hg, jj);
        float w;
        if (mat == 0)      w = f_Wh[(l * 32 + c) * 32 + m];
        else if (mat == 1) w = g_Wh[(l * 32 + c) * 32 + m];
        else               w = g_Wz[(l * 64 + c) * 32 + m];
        sImg[idx] = f2bf(w * INV2PI);
    }
    __syncthreads();

    // P2: encoder stage 2 + prescaled fz0p/fz1p + dWp
    if (tid < 32) {
        float a = xb2[tid];
        for (int c = 0; c < 32; ++c) a = fmaf(shx[c], xW2[c * 32 + tid], a);
        sex[tid] = a;
    } else if (tid < 64) {
        int d = tid - 32;
        float a = tb2[d];
        for (int c = 0; c < 32; ++c) a = fmaf(sht[c], tW2[c * 32 + d], a);
        set_[d] = a;
    }
    if (tid < 192) {
        int l = tid >> 5, p = tid & 31, d = Qmap(p);
        sfz0p[tid] = f_Wz[(l * 34 + 0) * 32 + d] * INV2PI;
        sfz1p[tid] = f_Wz[(l * 34 + 1) * 32 + d] * INV2PI;
    }
    if (tid < 32) sdWp[tid] = d_W[Qmap(tid)];
    __syncthreads();

    // P3: Cf and Cg (permuted, prescaled; h0/gh0 matvecs folded into l=0)
    if (tid < 192) {
        int l = tid >> 5, p = tid & 31, d = Qmap(p);
        float a = f_bh[l * 32 + d] + f_bz[l * 32 + d];
        for (int c = 0; c < 32; ++c) a = fmaf(set_[c], f_Wz[(l * 34 + 2 + c) * 32 + d], a);
        if (l == 0)
            for (int c = 0; c < 32; ++c) a = fmaf(h0[c], f_Wh[c * 32 + d], a);
        rawCfP[tid] = a * INV2PI;
        float g = g_bh[l * 32 + d] + g_bz[l * 32 + d];
        for (int c = 0; c < 32; ++c) g = fmaf(sex[c], g_Wz[(l * 64 + 32 + c) * 32 + d], g);
        if (l == 0)
            for (int c = 0; c < 32; ++c) g = fmaf(gh0[c], g_Wh[c * 32 + d], g);
        sCgp[tid] = g * INV2PI;
    }
    __syncthreads();

    // P4: per-wave Cfi = rawCfP + ti*fz1p (both already prescaled)
    for (int idx = tid; idx < 1536; idx += 512) {
        int w = idx / 192, r2 = idx % 192;
        float ti = coords[(b * 256 + ig * 8 + w) * 2 + 1];
        sCfi[idx] = fmaf(ti, sfz1p[r2], rawCfP[r2]);
    }
    __syncthreads();

    // ================= MAIN =================
    const int lane = tid & 63, wave = tid >> 6;
    const int i = ig * 8 + wave;
    const int e = lane & 31, hk = lane >> 5;
    const int pb = hk * 16;
    const float db = d_b[0];
    const float* cfiW = &sCfi[wave * 192];

    #pragma unroll 1
    for (int t = 0; t < 4; ++t) {
        const int tile = jg * 4 + t;
        const int j = tile * 32 + e;
        const float xj = coords[(b * 256 + j) * 2];

        floatx16 acc;
        short8 hB1h, hB1l, hB2h, hB2l;

        // ---- f layer 0: h0 term folded into Cfi -> no MFMA ----
        {
            const float* cfi = cfiW + pb;
            const float* z0  = &sfz0p[pb];
            #pragma unroll
            for (int r = 0; r < 16; ++r) acc[r] = fmaf(xj, z0[r], cfi[r]);
            sinsplit(acc, hB1h, hB1l, hB2h, hB2l);
        }
        // ---- f layers 1..5 ----
        for (int l = 1; l < NB; ++l) {
            const float* cfi = cfiW + l * 32 + pb;
            const float* z0  = &sfz0p[l * 32 + pb];
            #pragma unroll
            for (int r = 0; r < 16; ++r) acc[r] = fmaf(xj, z0[r], cfi[r]);
            const unsigned short* base = &sImg[(l * 2) * 512 + lane * 8];
            short8 ah0 = *(const short8*)(base);
            short8 ah1 = *(const short8*)(base + 512);
            acc = MFMA(ah0, hB1h, acc);
            acc = MFMA(ah0, hB1l, acc);
            acc = MFMA(ah1, hB2h, acc);
            acc = MFMA(ah1, hB2l, acc);
            sinsplit(acc, hB1h, hB1l, hB2h, hB2l);
        }

        // ---- g layer 0: gh0 term folded into Cg -> only Wz MFMAs ----
        short8 gB1h, gB1l, gB2h, gB2l;
        {
            const float* cg = &sCgp[pb];
            #pragma unroll
            for (int r = 0; r < 16; ++r) acc[r] = cg[r];
            const unsigned short* bz = &sImg[12288 + lane * 8];
            short8 wz0 = *(const short8*)(bz);
            short8 wz1 = *(const short8*)(bz + 512);
            acc = MFMA(wz0, hB1h, acc);
            acc = MFMA(wz0, hB1l, acc);
            acc = MFMA(wz1, hB2h, acc);
            acc = MFMA(wz1, hB2l, acc);
            sinsplit(acc, gB1h, gB1l, gB2h, gB2l);
        }
        // ---- g layers 1..5 ----
        for (int l = 1; l < NB; ++l) {
            const float* cg = &sCgp[l * 32 + pb];
            #pragma unroll
            for (int r = 0; r < 16; ++r) acc[r] = cg[r];
            {
                const unsigned short* bh = &sImg[6144 + (l * 2) * 512 + lane * 8];
                short8 wh0 = *(const short8*)(bh);
                short8 wh1 = *(const short8*)(bh + 512);
                acc = MFMA(wh0, gB1h, acc);
                acc = MFMA(wh0, gB1l, acc);
                acc = MFMA(wh1, gB2h, acc);
                acc = MFMA(wh1, gB2l, acc);
            }
            __builtin_amdgcn_sched_barrier(0);
            {
                const unsigned short* bz = &sImg[12288 + (l * 2) * 512 + lane * 8];
                short8 wz0 = *(const short8*)(bz);
                short8 wz1 = *(const short8*)(bz + 512);
                acc = MFMA(wz0, hB1h, acc);
                acc = MFMA(wz0, hB1l, acc);
                acc = MFMA(wz1, hB2h, acc);
                acc = MFMA(wz1, hB2l, acc);
            }
            if (l < NB - 1) sinsplit(acc, gB1h, gB1l, gB2h, gB2l);
        }

        // ---- decode ----
        float u = 0.0f;
        #pragma unroll
        for (int r = 0; r < 16; ++r) u = fmaf(__builtin_amdgcn_sinf(acc[r]), sdWp[pb + r], u);
        u += __shfl_xor(u, 32);
        if (hk == 0) out[(b * 256 + i) * 256 + j] = u + db;
    }
}

extern "C" void kernel_launch(void* const* d_in, const int* in_sizes, int n_in,
                              void* d_out, int out_size, void* d_ws, size_t ws_size,
                              hipStream_t stream) {
    const float* coords   = (const float*)d_in[0];
    const float* x_params = (const float*)d_in[1];
    const float* t_params = (const float*)d_in[2];
    const float* xW1 = (const float*)d_in[3];
    const float* xb1 = (const float*)d_in[4];
    const float* xW2 = (const float*)d_in[5];
    const float* xb2 = (const float*)d_in[6];
    const float* tW1 = (const float*)d_in[7];
    const float* tb1 = (const float*)d_in[8];
    const float* tW2 = (const float*)d_in[9];
    const float* tb2 = (const float*)d_in[10];
    const float* h0  = (const float*)d_in[11];
    const float* gh0 = (const float*)d_in[12];
    const float* f_Wh = (const float*)d_in[13];
    const float* f_bh = (const float*)d_in[14];
    const float* f_Wz = (const float*)d_in[15];
    const float* f_bz = (const float*)d_in[16];
    const float* g_Wh = (const float*)d_in[17];
    const float* g_bh = (const float*)d_in[18];
    const float* g_Wz = (const float*)d_in[19];
    const float* g_bz = (const float*)d_in[20];
    const float* d_W  = (const float*)d_in[21];
    const float* d_b  = (const float*)d_in[22];

    hipFuncSetAttribute((const void*)sep_mfma,
                        hipFuncAttributeMaxDynamicSharedMemorySize, LDS_BYTES);

    // 16 batches * 32 i-groups * 2 j-halves = 1024 blocks of 512 threads
    sep_mfma<<<1024, 512, LDS_BYTES, stream>>>(
        coords, x_params, t_params, xW1, xb1, xW2, xb2, tW1, tb1, tW2, tb2,
        h0, gh0, f_Wh, f_bh, f_Wz, f_bz, g_Wh, g_bh, g_Wz, g_bz, d_W, d_b,
        (float*)d_out);
}

// Round 8
// 198.064 us; speedup vs baseline: 3.4523x; 1.0145x over previous
//
#include <hip/hip_runtime.h>

#define DIM 32
#define NB  6
#define INV2PI 0.15915494309189535f

typedef __attribute__((ext_vector_type(8)))  short short8;
typedef __attribute__((ext_vector_type(16))) float floatx16;

union S8I4 { short8 s; int i[4]; };

__device__ __forceinline__ unsigned short f2bf(float f) {   // RNE
    unsigned u = __float_as_uint(f);
    return (unsigned short)((u + 0x7FFF + ((u >> 16) & 1)) >> 16);
}
__device__ __forceinline__ float bf2f(unsigned short b) {
    return __uint_as_float(((unsigned)b) << 16);
}
// B-frag slot (s,h,j) holds raw channel P; C/D reg (r,h) holds raw channel Q.
__device__ __forceinline__ int Pmap(int s, int h, int j) { return 16*s + 8*(j>>2) + 4*h + (j&3); }
__device__ __forceinline__ int Qmap(int p)               { int r = p & 15, h = p >> 4; return 8*(r>>2) + 4*h + (r&3); }

#define MFMA(a, b, c) __builtin_amdgcn_mfma_f32_32x32x16_bf16((a), (b), (c), 0, 0, 0)

// acc is in revolution domain (weights prescaled by 1/2pi):
// raw v_sin, then truncation hi/lo bf16 split packed via v_perm.
__device__ __forceinline__ void sinsplit(const floatx16& acc,
                                         short8& b1h, short8& b1l,
                                         short8& b2h, short8& b2l) {
    S8I4 nh1, nl1, nh2, nl2;
    #pragma unroll
    for (int q = 0; q < 4; ++q) {
        float s0 = __builtin_amdgcn_sinf(acc[2*q]), s1 = __builtin_amdgcn_sinf(acc[2*q+1]);
        unsigned a0 = __float_as_uint(s0), a1 = __float_as_uint(s1);
        nh1.i[q] = __builtin_amdgcn_perm(a1, a0, 0x07060302u);
        float l0 = s0 - __uint_as_float(a0 & 0xFFFF0000u);
        float l1 = s1 - __uint_as_float(a1 & 0xFFFF0000u);
        nl1.i[q] = __builtin_amdgcn_perm(__float_as_uint(l1), __float_as_uint(l0), 0x07060302u);
        float t0 = __builtin_amdgcn_sinf(acc[8+2*q]), t1 = __builtin_amdgcn_sinf(acc[8+2*q+1]);
        unsigned c0 = __float_as_uint(t0), c1 = __float_as_uint(t1);
        nh2.i[q] = __builtin_amdgcn_perm(c1, c0, 0x07060302u);
        float m0 = t0 - __uint_as_float(c0 & 0xFFFF0000u);
        float m1 = t1 - __uint_as_float(c1 & 0xFFFF0000u);
        nl2.i[q] = __builtin_amdgcn_perm(__float_as_uint(m1), __float_as_uint(m0), 0x07060302u);
    }
    b1h = nh1.s; b1l = nl1.s; b2h = nh2.s; b2l = nl2.s;
}

// LDS: 928 floats (3712 B) + 16384 shorts (32768 B) = 36480 B -> 4 blocks/CU.
#define LDS_BYTES 36480

// NOTE (measured R4/R5): __launch_bounds__ arg2 = min BLOCKS/CU on this
// toolchain. (512,4) -> 64-VGPR cap; R7 body ran at 52 VGPRs, fits.
// Spill tripwire: hbm_bytes (clean ~5 MB; spilled was ~1 GB).
__global__ __launch_bounds__(512, 4) void sep_mfma(
    const float* __restrict__ coords,
    const float* __restrict__ x_params,
    const float* __restrict__ t_params,
    const float* __restrict__ xW1, const float* __restrict__ xb1,
    const float* __restrict__ xW2, const float* __restrict__ xb2,
    const float* __restrict__ tW1, const float* __restrict__ tb1,
    const float* __restrict__ tW2, const float* __restrict__ tb2,
    const float* __restrict__ h0,  const float* __restrict__ gh0,
    const float* __restrict__ f_Wh, const float* __restrict__ f_bh,
    const float* __restrict__ f_Wz, const float* __restrict__ f_bz,
    const float* __restrict__ g_Wh, const float* __restrict__ g_bh,
    const float* __restrict__ g_Wz, const float* __restrict__ g_bz,
    const float* __restrict__ d_W,  const float* __restrict__ d_b,
    float* __restrict__ out)
{
    extern __shared__ char smem[];
    float* sfz0p  = (float*)smem;            // [6][32] fz0/2pi (permuted)
    float* sfz1p  = sfz0p + 192;             // [6][32] fz1/2pi (permuted)
    float* sCgp   = sfz1p + 192;             // [6][32] Cg/2pi (permuted, +gh0 fold at l=0)
    float* rawCfP = sCgp + 192;              // [6][32] Cf/2pi (permuted, +h0 fold at l=0)
    float* sdWp   = rawCfP + 192;            // [32] d_W (permuted, NOT scaled)
    float* shx    = sdWp + 32;
    float* sht    = shx + 32;
    float* sex    = sht + 32;
    float* set_   = sex + 32;
    // image: [f_Wh l=1..5 | g_Wh l=1..5 | g_Wz l=0..5] x [2 s-halves x 512]
    unsigned short* sImg = (unsigned short*)(set_ + 32);   // 16 slots * 1024 shorts

    const int tid = threadIdx.x;
    const int b   = blockIdx.x >> 6;          // 64 blocks per batch
    const int ig  = (blockIdx.x >> 1) & 31;   // i-group: 8 i's per block
    const int jg  = blockIdx.x & 1;           // j-half: 4 tiles per block

    // ================= PROLOGUE =================
    // P1: encoder stage 1 + A-frag image build (hi-only RNE bf16, prescaled,
    // packed 2 channels per int store; l=0 of f_Wh/g_Wh folded -> omitted)
    if (tid < 32) {
        float a = xb1[tid];
        for (int k = 0; k < 16; ++k) a = fmaf(x_params[b * 16 + k], xW1[k * 32 + tid], a);
        shx[tid] = __sinf(a);
    } else if (tid < 64) {
        int d = tid - 32;
        float a = tb1[d];
        for (int k = 0; k < 8; ++k) a = fmaf(t_params[b * 8 + k], tW1[k * 32 + d], a);
        sht[d] = __sinf(a);
    }
    {
        int* sImgI = (int*)sImg;
        for (int ii = tid; ii < 8192; ii += 512) {
            int region = ii >> 9;             // slot index 0..15 (block-uniform)
            int r = ii & 511;
            int s = r >> 8, t = r & 255;
            int lane = t >> 2, jj2 = t & 3;
            int m = lane & 31, hg = lane >> 5;
            int c0 = 16*s + 8*(jj2 >> 1) + 4*hg + 2*(jj2 & 1);  // Pmap(s,hg,2*jj2)
            float w0, w1;
            if (region < 5)       { int l = region + 1;  w0 = f_Wh[(l*32 + c0)*32 + m]; w1 = f_Wh[(l*32 + c0 + 1)*32 + m]; }
            else if (region < 10) { int l = region - 4;  w0 = g_Wh[(l*32 + c0)*32 + m]; w1 = g_Wh[(l*32 + c0 + 1)*32 + m]; }
            else                  { int l = region - 10; w0 = g_Wz[(l*64 + c0)*32 + m]; w1 = g_Wz[(l*64 + c0 + 1)*32 + m]; }
            unsigned p0 = f2bf(w0 * INV2PI), p1 = f2bf(w1 * INV2PI);
            sImgI[ii] = (int)(p0 | (p1 << 16));
        }
    }
    __syncthreads();

    // P2: encoder stage 2 + prescaled fz0p/fz1p + dWp
    if (tid < 32) {
        float a = xb2[tid];
        for (int c = 0; c < 32; ++c) a = fmaf(shx[c], xW2[c * 32 + tid], a);
        sex[tid] = a;
    } else if (tid < 64) {
        int d = tid - 32;
        float a = tb2[d];
        for (int c = 0; c < 32; ++c) a = fmaf(sht[c], tW2[c * 32 + d], a);
        set_[d] = a;
    }
    if (tid < 192) {
        int l = tid >> 5, p = tid & 31, d = Qmap(p);
        sfz0p[tid] = f_Wz[(l * 34 + 0) * 32 + d] * INV2PI;
        sfz1p[tid] = f_Wz[(l * 34 + 1) * 32 + d] * INV2PI;
    }
    if (tid < 32) sdWp[tid] = d_W[Qmap(tid)];
    __syncthreads();

    // P3: Cf and Cg (permuted, prescaled; h0/gh0 matvecs folded into l=0)
    if (tid < 192) {
        int l = tid >> 5, p = tid & 31, d = Qmap(p);
        float a = f_bh[l * 32 + d] + f_bz[l * 32 + d];
        for (int c = 0; c < 32; ++c) a = fmaf(set_[c], f_Wz[(l * 34 + 2 + c) * 32 + d], a);
        if (l == 0)
            for (int c = 0; c < 32; ++c) a = fmaf(h0[c], f_Wh[c * 32 + d], a);
        rawCfP[tid] = a * INV2PI;
        float g = g_bh[l * 32 + d] + g_bz[l * 32 + d];
        for (int c = 0; c < 32; ++c) g = fmaf(sex[c], g_Wz[(l * 64 + 32 + c) * 32 + d], g);
        if (l == 0)
            for (int c = 0; c < 32; ++c) g = fmaf(gh0[c], g_Wh[c * 32 + d], g);
        sCgp[tid] = g * INV2PI;
    }
    __syncthreads();

    // ================= MAIN =================
    const int lane = tid & 63, wave = tid >> 6;
    const int i = ig * 8 + wave;
    const int e = lane & 31, hk = lane >> 5;
    const int pb = hk * 16;
    const float ti = coords[(b * 256 + i) * 2 + 1];
    const float db = d_b[0];

    #pragma unroll 1
    for (int t = 0; t < 4; ++t) {
        const int tile = jg * 4 + t;
        const int j = tile * 32 + e;
        const float xj = coords[(b * 256 + j) * 2];

        floatx16 acc;
        short8 hB1h, hB1l, hB2h, hB2l;

        // ---- f layer 0: h0 term folded into Cf -> no MFMA ----
        {
            const float* cf = &rawCfP[pb];
            const float* z0 = &sfz0p[pb];
            const float* z1 = &sfz1p[pb];
            #pragma unroll
            for (int r = 0; r < 16; ++r) acc[r] = fmaf(xj, z0[r], fmaf(ti, z1[r], cf[r]));
            sinsplit(acc, hB1h, hB1l, hB2h, hB2l);
        }
        // ---- f layers 1..5 ----
        for (int l = 1; l < NB; ++l) {
            const float* cf = &rawCfP[l * 32 + pb];
            const float* z0 = &sfz0p[l * 32 + pb];
            const float* z1 = &sfz1p[l * 32 + pb];
            #pragma unroll
            for (int r = 0; r < 16; ++r) acc[r] = fmaf(xj, z0[r], fmaf(ti, z1[r], cf[r]));
            const unsigned short* base = &sImg[((l - 1) * 2) * 512 + lane * 8];
            short8 ah0 = *(const short8*)(base);
            short8 ah1 = *(const short8*)(base + 512);
            acc = MFMA(ah0, hB1h, acc);
            acc = MFMA(ah0, hB1l, acc);
            acc = MFMA(ah1, hB2h, acc);
            acc = MFMA(ah1, hB2l, acc);
            sinsplit(acc, hB1h, hB1l, hB2h, hB2l);
        }

        // ---- g layer 0: gh0 term folded into Cg -> only Wz MFMAs ----
        short8 gB1h, gB1l, gB2h, gB2l;
        {
            const float* cg = &sCgp[pb];
            #pragma unroll
            for (int r = 0; r < 16; ++r) acc[r] = cg[r];
            const unsigned short* bz = &sImg[10240 + lane * 8];
            short8 wz0 = *(const short8*)(bz);
            short8 wz1 = *(const short8*)(bz + 512);
            acc = MFMA(wz0, hB1h, acc);
            acc = MFMA(wz0, hB1l, acc);
            acc = MFMA(wz1, hB2h, acc);
            acc = MFMA(wz1, hB2l, acc);
            sinsplit(acc, gB1h, gB1l, gB2h, gB2l);
        }
        // ---- g layers 1..5 ----
        for (int l = 1; l < NB; ++l) {
            const float* cg = &sCgp[l * 32 + pb];
            #pragma unroll
            for (int r = 0; r < 16; ++r) acc[r] = cg[r];
            {
                const unsigned short* bh = &sImg[5120 + ((l - 1) * 2) * 512 + lane * 8];
                short8 wh0 = *(const short8*)(bh);
                short8 wh1 = *(const short8*)(bh + 512);
                acc = MFMA(wh0, gB1h, acc);
                acc = MFMA(wh0, gB1l, acc);
                acc = MFMA(wh1, gB2h, acc);
                acc = MFMA(wh1, gB2l, acc);
            }
            __builtin_amdgcn_sched_barrier(0);
            {
                const unsigned short* bz = &sImg[10240 + (l * 2) * 512 + lane * 8];
                short8 wz0 = *(const short8*)(bz);
                short8 wz1 = *(const short8*)(bz + 512);
                acc = MFMA(wz0, hB1h, acc);
                acc = MFMA(wz0, hB1l, acc);
                acc = MFMA(wz1, hB2h, acc);
                acc = MFMA(wz1, hB2l, acc);
            }
            if (l < NB - 1) sinsplit(acc, gB1h, gB1l, gB2h, gB2l);
        }

        // ---- decode ----
        float u = 0.0f;
        #pragma unroll
        for (int r = 0; r < 16; ++r) u = fmaf(__builtin_amdgcn_sinf(acc[r]), sdWp[pb + r], u);
        u += __shfl_xor(u, 32);
        if (hk == 0) out[(b * 256 + i) * 256 + j] = u + db;
    }
}

extern "C" void kernel_launch(void* const* d_in, const int* in_sizes, int n_in,
                              void* d_out, int out_size, void* d_ws, size_t ws_size,
                              hipStream_t stream) {
    const float* coords   = (const float*)d_in[0];
    const float* x_params = (const float*)d_in[1];
    const float* t_params = (const float*)d_in[2];
    const float* xW1 = (const float*)d_in[3];
    const float* xb1 = (const float*)d_in[4];
    const float* xW2 = (const float*)d_in[5];
    const float* xb2 = (const float*)d_in[6];
    const float* tW1 = (const float*)d_in[7];
    const float* tb1 = (const float*)d_in[8];
    const float* tW2 = (const float*)d_in[9];
    const float* tb2 = (const float*)d_in[10];
    const float* h0  = (const float*)d_in[11];
    const float* gh0 = (const float*)d_in[12];
    const float* f_Wh = (const float*)d_in[13];
    const float* f_bh = (const float*)d_in[14];
    const float* f_Wz = (const float*)d_in[15];
    const float* f_bz = (const float*)d_in[16];
    const float* g_Wh = (const float*)d_in[17];
    const float* g_bh = (const float*)d_in[18];
    const float* g_Wz = (const float*)d_in[19];
    const float* g_bz = (const float*)d_in[20];
    const float* d_W  = (const float*)d_in[21];
    const float* d_b  = (const float*)d_in[22];

    hipFuncSetAttribute((const void*)sep_mfma,
                        hipFuncAttributeMaxDynamicSharedMemorySize, LDS_BYTES);

    // 16 batches * 32 i-groups * 2 j-halves = 1024 blocks of 512 threads
    // -> exactly 4 blocks/CU, fully co-resident
    sep_mfma<<<1024, 512, LDS_BYTES, stream>>>(
        coords, x_params, t_params, xW1, xb1, xW2, xb2, tW1, tb1, tW2, tb2,
        h0, gh0, f_Wh, f_bh, f_Wz, f_bz, g_Wh, g_bh, g_Wz, g_bz, d_W, d_b,
        (float*)d_out);
}